// Round 11
// baseline (268.471 us; speedup 1.0000x reference)
//
#include <hip/hip_runtime.h>

typedef unsigned short ushort_t;
using frag_ab = __attribute__((ext_vector_type(8))) short;
using f32x4   = __attribute__((ext_vector_type(4))) float;
using f32x2   = __attribute__((ext_vector_type(2))) float;
using u32x4   = __attribute__((ext_vector_type(4))) unsigned int;

#define FDIM 512
#define NH 8
#define FATT 64
#define NX 2048
#define NP 4096
#define NTOT 6144
#define NSLICE 4
#define PSLICE (NP / NSLICE)   // 1024

__device__ __forceinline__ ushort_t f2bf(float f) {
    unsigned u = __float_as_uint(f);
    u = (u + 0x7FFFu + ((u >> 16) & 1u)) >> 16;   // RTNE
    return (ushort_t)u;
}
__device__ __forceinline__ float bf2f(ushort_t s) {
    return __uint_as_float(((unsigned)s) << 16);
}
__device__ __forceinline__ unsigned pk2bf(float a, float b) {
    return (unsigned)f2bf(a) | ((unsigned)f2bf(b) << 16);
}

// ---------------------------------------------------------------------------
// K0: fp32 -> bf16 conversions: f = concat(fx, fp0), Wembd, Wfc, Wout
// ---------------------------------------------------------------------------
__global__ __launch_bounds__(256) void k_prep(const float* __restrict__ fx,
                                              const float* __restrict__ fp,
                                              const float* __restrict__ We,
                                              const float* __restrict__ Wfc,
                                              const float* __restrict__ Wout,
                                              ushort_t* __restrict__ f_b,
                                              ushort_t* __restrict__ We_b,
                                              ushort_t* __restrict__ Wfc_b,
                                              ushort_t* __restrict__ Wout_b) {
    int i = blockIdx.x * 256 + threadIdx.x;
    int stride = gridDim.x * 256;
    const int NF4 = NTOT * FDIM / 4;
    const int NX4 = NX * FDIM / 4;
    for (int idx = i; idx < NF4; idx += stride) {
        float4 v = (idx < NX4) ? ((const float4*)fx)[idx]
                               : ((const float4*)fp)[idx - NX4];
        ushort4 o;
        o.x = f2bf(v.x); o.y = f2bf(v.y); o.z = f2bf(v.z); o.w = f2bf(v.w);
        ((ushort4*)f_b)[idx] = o;
    }
    const int NW4 = FDIM * FDIM / 4;
    for (int idx = i; idx < NW4; idx += stride) {
        float4 v = ((const float4*)We)[idx];
        ushort4 o;
        o.x = f2bf(v.x); o.y = f2bf(v.y); o.z = f2bf(v.z); o.w = f2bf(v.w);
        ((ushort4*)We_b)[idx] = o;
    }
    const int NFC4 = NH * FATT * 2 * FATT / 4;
    for (int idx = i; idx < NFC4; idx += stride) {
        float4 v = ((const float4*)Wfc)[idx];
        ushort4 o;
        o.x = f2bf(v.x); o.y = f2bf(v.y); o.z = f2bf(v.z); o.w = f2bf(v.w);
        ((ushort4*)Wfc_b)[idx] = o;
    }
    for (int idx = i; idx < NW4; idx += stride) {
        float4 v = ((const float4*)Wout)[idx];
        ushort4 o;
        o.x = f2bf(v.x); o.y = f2bf(v.y); o.z = f2bf(v.z); o.w = f2bf(v.w);
        ((ushort4*)Wout_b)[idx] = o;
    }
}

// ---------------------------------------------------------------------------
// K1: femb[h][n][e] = f[n] . Wembd[h][e] + bembd  (MFMA GEMM, bf16 out)
//     also writes fpT[h][e][p] (n>=NX) and facat[h][x][64+e] (n<NX)
// ---------------------------------------------------------------------------
__global__ __launch_bounds__(256) void k_embed(const ushort_t* __restrict__ f_b,
                                               const ushort_t* __restrict__ We_b,
                                               const float* __restrict__ bembd,
                                               ushort_t* __restrict__ femb_b,
                                               ushort_t* __restrict__ fpT_b,
                                               ushort_t* __restrict__ facat_b) {
    int tid = threadIdx.x;
    int wv = tid >> 6, lane = tid & 63;
    int g = lane >> 4, c = lane & 15;
    int m0 = blockIdx.x * 64 + wv * 16;
    int o0 = blockIdx.y * 64;

    f32x4 acc[4] = {};
    const ushort_t* arow = f_b + (size_t)(m0 + c) * FDIM + g * 8;
#pragma unroll 4
    for (int ks = 0; ks < FDIM; ks += 32) {
        frag_ab a = *(const frag_ab*)(arow + ks);
#pragma unroll
        for (int t = 0; t < 4; ++t) {
            const ushort_t* brow = We_b + (size_t)(o0 + t * 16 + c) * FDIM + ks + g * 8;
            frag_ab b = *(const frag_ab*)brow;
            acc[t] = __builtin_amdgcn_mfma_f32_16x16x32_bf16(a, b, acc[t], 0, 0, 0);
        }
    }
#pragma unroll
    for (int t = 0; t < 4; ++t) {
        int o = o0 + t * 16 + c;           // output feature = h*64+e
        int h = o >> 6, e = o & 63;
        float bia = bembd[o];
#pragma unroll
        for (int r = 0; r < 4; ++r) {
            int n = m0 + g * 4 + r;
            ushort_t v = f2bf(acc[t][r] + bia);
            femb_b[((size_t)h * NTOT + n) * FATT + e] = v;
            if (n >= NX) fpT_b[((size_t)h * FATT + e) * NP + (n - NX)] = v;
            else         facat_b[((size_t)h * NX + n) * 128 + 64 + e] = v;
        }
    }
}

// ---------------------------------------------------------------------------
// K2a: attention pass-1 partials — shuffle-based, NO LDS, NO barriers.
//   Swapped QK (D rows = p, cols = x); P relaid to PV A-fragment via
//   ds_bpermute. 4 independent waves per block; h = bid%8 (XCD affinity).
// ---------------------------------------------------------------------------
__global__ __launch_bounds__(256) void k_attn_part(const ushort_t* __restrict__ femb_b,
                                                   const ushort_t* __restrict__ fpT_b,
                                                   float* __restrict__ part_sum,
                                                   float* __restrict__ part_pv) {
    int bid = blockIdx.x;
    int h  = bid & 7;
    int wv = threadIdx.x >> 6;
    int t1 = (bid >> 3) * 4 + wv;      // 0..511
    int xt = t1 & 127;
    int sl = t1 >> 7;                  // 0..NSLICE-1
    int lane = threadIdx.x & 63;
    int g = lane >> 4, c = lane & 15;

    const ushort_t* fxb = femb_b + (size_t)h * NTOT * FATT;
    const ushort_t* fpb = fxb + (size_t)NX * FATT;
    const ushort_t* fTb = fpT_b + (size_t)h * FATT * NP;

    // QK B-operand: fx cols (x = xt*16 + c), k = e
    const ushort_t* brow = fxb + (size_t)(xt * 16 + c) * FATT + g * 8;
    frag_ab bx0 = *(const frag_ab*)(brow);
    frag_ab bx1 = *(const frag_ab*)(brow + 32);

    f32x4 pacc[4] = {};
    float rsum = 0.f;                  // per-lane partial for x = c

    // bpermute byte-addrs: sources for PV A-frag of target lane (g,c)
    int la4 = (c + ((g & 1) << 5)) << 2;   // lane c + 32*(g&1)
    int lb4 = la4 + 64;                    // +16 lanes
    int use_hi = g >> 1;

    const int p0 = sl * PSLICE;
    for (int ps = p0; ps < p0 + PSLICE; ps += 32) {
        unsigned tw[2][2];
#pragma unroll
        for (int t = 0; t < 2; ++t) {
            // swapped QK: A = fp rows (p = ps+16t+c), k = e
            const ushort_t* arow = fpb + (size_t)(ps + t * 16 + c) * FATT + g * 8;
            f32x4 s = {};
            s = __builtin_amdgcn_mfma_f32_16x16x32_bf16(*(const frag_ab*)arow, bx0, s, 0, 0, 0);
            s = __builtin_amdgcn_mfma_f32_16x16x32_bf16(*(const frag_ab*)(arow + 32), bx1, s, 0, 0, 0);
            // lane holds ev for p = ps+16t+4g+r, x = c
            float e0 = __expf(s[0] * 0.125f);
            float e1 = __expf(s[1] * 0.125f);
            float e2 = __expf(s[2] * 0.125f);
            float e3 = __expf(s[3] * 0.125f);
            rsum += (e0 + e1) + (e2 + e3);
            tw[t][0] = pk2bf(e0, e1);
            tw[t][1] = pk2bf(e2, e3);
        }
        // PV A-frag for lane (g,c): bf16[j] = P[x=c][p = ps+8g+j]
        unsigned A0 = __builtin_amdgcn_ds_bpermute(la4, (int)tw[0][0]);
        unsigned A1 = __builtin_amdgcn_ds_bpermute(la4, (int)tw[0][1]);
        unsigned A2 = __builtin_amdgcn_ds_bpermute(lb4, (int)tw[0][0]);
        unsigned A3 = __builtin_amdgcn_ds_bpermute(lb4, (int)tw[0][1]);
        unsigned B0 = __builtin_amdgcn_ds_bpermute(la4, (int)tw[1][0]);
        unsigned B1 = __builtin_amdgcn_ds_bpermute(la4, (int)tw[1][1]);
        unsigned B2 = __builtin_amdgcn_ds_bpermute(lb4, (int)tw[1][0]);
        unsigned B3 = __builtin_amdgcn_ds_bpermute(lb4, (int)tw[1][1]);
        u32x4 paw;
        paw[0] = use_hi ? B0 : A0;
        paw[1] = use_hi ? B1 : A1;
        paw[2] = use_hi ? B2 : A2;
        paw[3] = use_hi ? B3 : A3;
        frag_ab pa = __builtin_bit_cast(frag_ab, paw);
#pragma unroll
        for (int t2 = 0; t2 < 4; ++t2) {
            const ushort_t* vrow = fTb + (size_t)(t2 * 16 + c) * NP + ps + g * 8;
            pacc[t2] = __builtin_amdgcn_mfma_f32_16x16x32_bf16(pa, *(const frag_ab*)vrow, pacc[t2], 0, 0, 0);
        }
    }

    // row-sum: reduce over lanes with same c (g bits = lane bits 4,5)
    rsum += __shfl_xor(rsum, 16);
    rsum += __shfl_xor(rsum, 32);

    size_t base = (((size_t)sl * NH + h) * 128 + xt) * 16;
    if (lane < 16) part_sum[base + c] = rsum;      // x = c
#pragma unroll
    for (int t2 = 0; t2 < 4; ++t2)
#pragma unroll
        for (int r = 0; r < 4; ++r)
            part_pv[(base + g * 4 + r) * 64 + t2 * 16 + c] = pacc[t2][r];
}

// ---------------------------------------------------------------------------
// K2c: combine partials -> facat bf16 + inv_sums. 4 waves per (xt, h).
// ---------------------------------------------------------------------------
__global__ __launch_bounds__(256) void k_attn_red(const float* __restrict__ part_sum,
                                                  const float* __restrict__ part_pv,
                                                  float* __restrict__ inv_sums,
                                                  ushort_t* __restrict__ facat_b) {
    int xt = blockIdx.x, h = blockIdx.y;
    int lane = threadIdx.x & 63;    // = e
    int w = threadIdx.x >> 6;       // wave 0..3

#pragma unroll
    for (int rr = 0; rr < 4; ++rr) {
        int r = w * 4 + rr;
        float stot = 0.f, val = 0.f;
#pragma unroll
        for (int sl = 0; sl < NSLICE; ++sl) {
            size_t base = (((size_t)sl * NH + h) * 128 + xt) * 16 + r;
            stot += part_sum[base];
            val  += part_pv[base * 64 + lane];
        }
        float inv = 1.f / stot;
        if (lane == 0) inv_sums[(size_t)h * NX + xt * 16 + r] = inv;
        facat_b[((size_t)h * NX + xt * 16 + r) * 128 + lane] = f2bf(val * inv);
    }
}

// ---------------------------------------------------------------------------
// K2b: w_out writer v4 — identical to v3 EXCEPT the final global stores are
//   NON-TEMPORAL (bypass L2/L3): w_out is never re-read on device, and 268MB
//   of regular write-allocate stores thrash the caches holding K/V.
// ---------------------------------------------------------------------------
__global__ __launch_bounds__(256) void k_wout(const ushort_t* __restrict__ femb_b,
                                              const float* __restrict__ inv_sums,
                                              float* __restrict__ w_out) {
    int bid = blockIdx.x;
    int h  = bid & 7;
    int wv = threadIdx.x >> 6;
    int t1 = (bid >> 3) * 4 + wv;      // 0..1023
    int xt = t1 & 127;
    int sl = t1 >> 7;                  // 0..7 (512-p slices)
    int lane = threadIdx.x & 63;
    int g = lane >> 4, c = lane & 15;

    __shared__ float lds[4][16][132];  // per-wave 16 x-rows x 128 p (pad 4)

    const ushort_t* fxb = femb_b + (size_t)h * NTOT * FATT;
    const ushort_t* fpb = fxb + (size_t)NX * FATT;

    // B = fx cols (x = xt*16 + c)
    const ushort_t* brow = fxb + (size_t)(xt * 16 + c) * FATT + g * 8;
    frag_ab b0 = *(const frag_ab*)(brow);
    frag_ab b1 = *(const frag_ab*)(brow + 32);
    float inv_c = inv_sums[(size_t)h * NX + xt * 16 + c];   // for x = c

    const int p0 = sl * 512;
    for (int chunk = 0; chunk < 512; chunk += 128) {
#pragma unroll
        for (int pt = 0; pt < 8; ++pt) {       // 16-p tiles within chunk
            int ps = p0 + chunk + pt * 16;
            const ushort_t* arow = fpb + (size_t)(ps + c) * FATT + g * 8;
            f32x4 s = {};
            s = __builtin_amdgcn_mfma_f32_16x16x32_bf16(*(const frag_ab*)arow, b0, s, 0, 0, 0);
            s = __builtin_amdgcn_mfma_f32_16x16x32_bf16(*(const frag_ab*)(arow + 32), b1, s, 0, 0, 0);
            // lane holds w for p = ps + 4g + r (r=0..3), x = c
            f32x4 ev;
            ev[0] = __expf(s[0] * 0.125f) * inv_c;
            ev[1] = __expf(s[1] * 0.125f) * inv_c;
            ev[2] = __expf(s[2] * 0.125f) * inv_c;
            ev[3] = __expf(s[3] * 0.125f) * inv_c;
            int sw = (pt * 16 + g * 4) ^ ((c & 7) << 4);   // XOR swizzle (16-f32 gran)
            *(f32x4*)&lds[wv][c][sw] = ev;
        }
        __syncthreads();   // all waves same trip count; orders LDS writes->reads
        // contiguous row writes: 64 lanes x f32x2 = 512B per instruction, NT
#pragma unroll
        for (int row = 0; row < 16; ++row) {
            int pi = lane * 2;
            int swr = pi ^ ((row & 7) << 4);
            f32x2 v = *(const f32x2*)&lds[wv][row][swr];
            float* dst = w_out + ((size_t)(xt * 16 + row) * NH + h) * NP + p0 + chunk + pi;
            __builtin_nontemporal_store(v, (f32x2*)dst);
        }
        __syncthreads();   // WAR before next chunk overwrites the tile
    }
}

// ---------------------------------------------------------------------------
// K3: fc — per-head MFMA GEMM (2048 x 64out x 128k), relu, bf16 out
// ---------------------------------------------------------------------------
__global__ __launch_bounds__(256) void k_fc(const ushort_t* __restrict__ facat_b,
                                            const ushort_t* __restrict__ Wfc_b,
                                            const float* __restrict__ bfc,
                                            ushort_t* __restrict__ fcout_b) {
    int tid = threadIdx.x;
    int wv = tid >> 6, lane = tid & 63;
    int g = lane >> 4, c = lane & 15;
    int x0 = blockIdx.x * 64 + wv * 16;
    int h = blockIdx.y;

    const ushort_t* A = facat_b + ((size_t)h * NX + x0 + c) * 128 + g * 8;
    const ushort_t* B = Wfc_b + (size_t)h * FATT * 128;

    f32x4 acc[4] = {};
#pragma unroll
    for (int ks = 0; ks < 128; ks += 32) {
        frag_ab a = *(const frag_ab*)(A + ks);
#pragma unroll
        for (int t = 0; t < 4; ++t) {
            frag_ab b = *(const frag_ab*)(B + (size_t)(t * 16 + c) * 128 + ks + g * 8);
            acc[t] = __builtin_amdgcn_mfma_f32_16x16x32_bf16(a, b, acc[t], 0, 0, 0);
        }
    }
#pragma unroll
    for (int t = 0; t < 4; ++t) {
        int e = t * 16 + c;
        float bia = bfc[h * FATT + e];
#pragma unroll
        for (int r = 0; r < 4; ++r) {
            int x = x0 + g * 4 + r;
            fcout_b[(size_t)x * FDIM + h * FATT + e] = f2bf(fmaxf(acc[t][r] + bia, 0.f));
        }
    }
}

// ---------------------------------------------------------------------------
// K4: out GEMM (2048 x 512 x 512) MFMA + residual + bias + relu (fp32 out)
// ---------------------------------------------------------------------------
__global__ __launch_bounds__(256) void k_out(const float* __restrict__ fx_in,
                                             const ushort_t* __restrict__ fcout_b,
                                             const ushort_t* __restrict__ Wout_b,
                                             const float* __restrict__ bout,
                                             float* __restrict__ out) {
    int tid = threadIdx.x;
    int wv = tid >> 6, lane = tid & 63;
    int g = lane >> 4, c = lane & 15;
    int x0 = blockIdx.x * 64 + wv * 16;
    int o0 = blockIdx.y * 64;

    f32x4 acc[4] = {};
    const ushort_t* A = fcout_b + (size_t)(x0 + c) * FDIM + g * 8;
#pragma unroll 4
    for (int ks = 0; ks < FDIM; ks += 32) {
        frag_ab a = *(const frag_ab*)(A + ks);
#pragma unroll
        for (int t = 0; t < 4; ++t) {
            frag_ab b = *(const frag_ab*)(Wout_b + (size_t)(o0 + t * 16 + c) * FDIM + ks + g * 8);
            acc[t] = __builtin_amdgcn_mfma_f32_16x16x32_bf16(a, b, acc[t], 0, 0, 0);
        }
    }
#pragma unroll
    for (int t = 0; t < 4; ++t) {
        int f = o0 + t * 16 + c;
        float bia = bout[f];
#pragma unroll
        for (int r = 0; r < 4; ++r) {
            int x = x0 + g * 4 + r;
            float v = acc[t][r] + bia + fx_in[(size_t)x * FDIM + f];
            out[(size_t)x * FDIM + f] = fmaxf(v, 0.f);
        }
    }
}

extern "C" void kernel_launch(void* const* d_in, const int* in_sizes, int n_in,
                              void* d_out, int out_size, void* d_ws, size_t ws_size,
                              hipStream_t stream) {
    const float* fx_in = (const float*)d_in[0];
    const float* fp_in = (const float*)d_in[1];
    const float* Wembd = (const float*)d_in[2];
    const float* bembd = (const float*)d_in[3];
    const float* Wfc   = (const float*)d_in[4];
    const float* bfc   = (const float*)d_in[5];
    const float* Wout  = (const float*)d_in[6];
    const float* bout  = (const float*)d_in[7];

    float* out   = (float*)d_out;
    float* w_out = out + (size_t)NX * FDIM;

    ushort_t* f_b     = (ushort_t*)d_ws;                     // 6144*512
    ushort_t* We_b    = f_b + (size_t)NTOT * FDIM;           // 512*512
    ushort_t* femb_b  = We_b + (size_t)FDIM * FDIM;          // 8*6144*64
    ushort_t* fpT_b   = femb_b + (size_t)NH * NTOT * FATT;   // 8*64*4096
    ushort_t* facat_b = fpT_b + (size_t)NH * FATT * NP;      // 8*2048*128
    ushort_t* fcout_b = facat_b + (size_t)NH * NX * 128;     // 2048*512
    ushort_t* Wfc_b   = fcout_b + (size_t)NX * FDIM;         // 8*64*128
    ushort_t* Wout_b  = Wfc_b + (size_t)NH * FATT * 2 * FATT;// 512*512
    float*    inv_sums= (float*)(Wout_b + (size_t)FDIM * FDIM); // 8*2048 f32
    float*    part_sum= inv_sums + (size_t)NH * NX;          // NSLICE*8*128*16 f32
    float*    part_pv = part_sum + (size_t)NSLICE * NH * 128 * 16; // *64 f32

    k_prep <<<1024, 256, 0, stream>>>(fx_in, fp_in, Wembd, Wfc, Wout,
                                      f_b, We_b, Wfc_b, Wout_b);
    k_embed<<<dim3(96, 8), 256, 0, stream>>>(f_b, We_b, bembd, femb_b, fpT_b, facat_b);
    k_attn_part<<<1024, 256, 0, stream>>>(femb_b, fpT_b, part_sum, part_pv);
    k_attn_red <<<dim3(128, 8), 256, 0, stream>>>(part_sum, part_pv, inv_sums, facat_b);
    k_wout <<<2048, 256, 0, stream>>>(femb_b, inv_sums, w_out);
    k_fc   <<<dim3(32, 8), 256, 0, stream>>>(facat_b, Wfc_b, bfc, fcout_b);
    k_out  <<<dim3(32, 8), 256, 0, stream>>>(fx_in, fcout_b, Wout_b, bout, out);
}

// Round 12
// 246.219 us; speedup vs baseline: 1.0904x; 1.0904x over previous
//
#include <hip/hip_runtime.h>

typedef unsigned short ushort_t;
using frag_ab = __attribute__((ext_vector_type(8))) short;
using f32x4   = __attribute__((ext_vector_type(4))) float;
using u32x4   = __attribute__((ext_vector_type(4))) unsigned int;

#define FDIM 512
#define NH 8
#define FATT 64
#define NX 2048
#define NP 4096
#define NTOT 6144

__device__ __forceinline__ ushort_t f2bf(float f) {
    unsigned u = __float_as_uint(f);
    u = (u + 0x7FFFu + ((u >> 16) & 1u)) >> 16;   // RTNE
    return (ushort_t)u;
}
__device__ __forceinline__ float bf2f(ushort_t s) {
    return __uint_as_float(((unsigned)s) << 16);
}
__device__ __forceinline__ unsigned pk2bf(float a, float b) {
    return (unsigned)f2bf(a) | ((unsigned)f2bf(b) << 16);
}

// ---------------------------------------------------------------------------
// K0: fp32 -> bf16 conversions: f = concat(fx, fp0), Wembd, Wfc, Wout
// ---------------------------------------------------------------------------
__global__ __launch_bounds__(256) void k_prep(const float* __restrict__ fx,
                                              const float* __restrict__ fp,
                                              const float* __restrict__ We,
                                              const float* __restrict__ Wfc,
                                              const float* __restrict__ Wout,
                                              ushort_t* __restrict__ f_b,
                                              ushort_t* __restrict__ We_b,
                                              ushort_t* __restrict__ Wfc_b,
                                              ushort_t* __restrict__ Wout_b) {
    int i = blockIdx.x * 256 + threadIdx.x;
    int stride = gridDim.x * 256;
    const int NF4 = NTOT * FDIM / 4;
    const int NX4 = NX * FDIM / 4;
    for (int idx = i; idx < NF4; idx += stride) {
        float4 v = (idx < NX4) ? ((const float4*)fx)[idx]
                               : ((const float4*)fp)[idx - NX4];
        ushort4 o;
        o.x = f2bf(v.x); o.y = f2bf(v.y); o.z = f2bf(v.z); o.w = f2bf(v.w);
        ((ushort4*)f_b)[idx] = o;
    }
    const int NW4 = FDIM * FDIM / 4;
    for (int idx = i; idx < NW4; idx += stride) {
        float4 v = ((const float4*)We)[idx];
        ushort4 o;
        o.x = f2bf(v.x); o.y = f2bf(v.y); o.z = f2bf(v.z); o.w = f2bf(v.w);
        ((ushort4*)We_b)[idx] = o;
    }
    const int NFC4 = NH * FATT * 2 * FATT / 4;
    for (int idx = i; idx < NFC4; idx += stride) {
        float4 v = ((const float4*)Wfc)[idx];
        ushort4 o;
        o.x = f2bf(v.x); o.y = f2bf(v.y); o.z = f2bf(v.z); o.w = f2bf(v.w);
        ((ushort4*)Wfc_b)[idx] = o;
    }
    for (int idx = i; idx < NW4; idx += stride) {
        float4 v = ((const float4*)Wout)[idx];
        ushort4 o;
        o.x = f2bf(v.x); o.y = f2bf(v.y); o.z = f2bf(v.z); o.w = f2bf(v.w);
        ((ushort4*)Wout_b)[idx] = o;
    }
}

// ---------------------------------------------------------------------------
// K1: femb[h][n][e] = f[n] . Wembd[h][e] + bembd  (MFMA GEMM, bf16 out)
//     also writes fpT[h][e][p] (n>=NX) and facat[h][x][64+e] (n<NX)
// ---------------------------------------------------------------------------
__global__ __launch_bounds__(256) void k_embed(const ushort_t* __restrict__ f_b,
                                               const ushort_t* __restrict__ We_b,
                                               const float* __restrict__ bembd,
                                               ushort_t* __restrict__ femb_b,
                                               ushort_t* __restrict__ fpT_b,
                                               ushort_t* __restrict__ facat_b) {
    int tid = threadIdx.x;
    int wv = tid >> 6, lane = tid & 63;
    int g = lane >> 4, c = lane & 15;
    int m0 = blockIdx.x * 64 + wv * 16;
    int o0 = blockIdx.y * 64;

    f32x4 acc[4] = {};
    const ushort_t* arow = f_b + (size_t)(m0 + c) * FDIM + g * 8;
#pragma unroll 4
    for (int ks = 0; ks < FDIM; ks += 32) {
        frag_ab a = *(const frag_ab*)(arow + ks);
#pragma unroll
        for (int t = 0; t < 4; ++t) {
            const ushort_t* brow = We_b + (size_t)(o0 + t * 16 + c) * FDIM + ks + g * 8;
            frag_ab b = *(const frag_ab*)brow;
            acc[t] = __builtin_amdgcn_mfma_f32_16x16x32_bf16(a, b, acc[t], 0, 0, 0);
        }
    }
#pragma unroll
    for (int t = 0; t < 4; ++t) {
        int o = o0 + t * 16 + c;           // output feature = h*64+e
        int h = o >> 6, e = o & 63;
        float bia = bembd[o];
#pragma unroll
        for (int r = 0; r < 4; ++r) {
            int n = m0 + g * 4 + r;
            ushort_t v = f2bf(acc[t][r] + bia);
            femb_b[((size_t)h * NTOT + n) * FATT + e] = v;
            if (n >= NX) fpT_b[((size_t)h * FATT + e) * NP + (n - NX)] = v;
            else         facat_b[((size_t)h * NX + n) * 128 + 64 + e] = v;
        }
    }
}

// ---------------------------------------------------------------------------
// K2: FUSED attention — one block per (xt, h), 8 waves, wave w owns a 512-p
//   slice. Pass 1: swapped QK + bpermute P-relay + PV partials (round-8
//   validated inner loop). Cross-wave combine in LDS (2 unconditional
//   barriers). Pass 2: recompute QK, exp*inv, NT float4 stores (round-7
//   validated inner loop). Writes facat bf16 + w_out.
// ---------------------------------------------------------------------------
__global__ __launch_bounds__(512) void k_attn_f(const ushort_t* __restrict__ femb_b,
                                                const ushort_t* __restrict__ fpT_b,
                                                float* __restrict__ w_out,
                                                ushort_t* __restrict__ facat_b) {
    int bid = blockIdx.x;
    int h  = bid & 7;                 // XCD affinity
    int xt = bid >> 3;                // 0..127
    int tid = threadIdx.x;
    int wv = tid >> 6;                // 0..7 -> p slice
    int lane = tid & 63;
    int g = lane >> 4, c = lane & 15;

    __shared__ float lds_pv[8][16][64];   // 32 KB: per-wave PV partials
    __shared__ float lds_sum[8][16];      // per-wave row sums
    __shared__ float lds_inv[16];

    const ushort_t* fxb = femb_b + (size_t)h * NTOT * FATT;
    const ushort_t* fpb = fxb + (size_t)NX * FATT;
    const ushort_t* fTb = fpT_b + (size_t)h * FATT * NP;

    // QK B-operand: fx cols (x = xt*16 + c), k = e
    const ushort_t* brow = fxb + (size_t)(xt * 16 + c) * FATT + g * 8;
    frag_ab bx0 = *(const frag_ab*)(brow);
    frag_ab bx1 = *(const frag_ab*)(brow + 32);

    f32x4 pacc[4] = {};
    float rsum = 0.f;                 // per-lane partial for x = c

    // bpermute byte-addrs for PV A-frag relay
    int la4 = (c + ((g & 1) << 5)) << 2;
    int lb4 = la4 + 64;
    int use_hi = g >> 1;

    const int p0 = wv * 512;
    for (int ps = p0; ps < p0 + 512; ps += 32) {
        unsigned tw[2][2];
#pragma unroll
        for (int t = 0; t < 2; ++t) {
            const ushort_t* arow = fpb + (size_t)(ps + t * 16 + c) * FATT + g * 8;
            f32x4 s = {};
            s = __builtin_amdgcn_mfma_f32_16x16x32_bf16(*(const frag_ab*)arow, bx0, s, 0, 0, 0);
            s = __builtin_amdgcn_mfma_f32_16x16x32_bf16(*(const frag_ab*)(arow + 32), bx1, s, 0, 0, 0);
            float e0 = __expf(s[0] * 0.125f);
            float e1 = __expf(s[1] * 0.125f);
            float e2 = __expf(s[2] * 0.125f);
            float e3 = __expf(s[3] * 0.125f);
            rsum += (e0 + e1) + (e2 + e3);
            tw[t][0] = pk2bf(e0, e1);
            tw[t][1] = pk2bf(e2, e3);
        }
        unsigned A0 = __builtin_amdgcn_ds_bpermute(la4, (int)tw[0][0]);
        unsigned A1 = __builtin_amdgcn_ds_bpermute(la4, (int)tw[0][1]);
        unsigned A2 = __builtin_amdgcn_ds_bpermute(lb4, (int)tw[0][0]);
        unsigned A3 = __builtin_amdgcn_ds_bpermute(lb4, (int)tw[0][1]);
        unsigned B0 = __builtin_amdgcn_ds_bpermute(la4, (int)tw[1][0]);
        unsigned B1 = __builtin_amdgcn_ds_bpermute(la4, (int)tw[1][1]);
        unsigned B2 = __builtin_amdgcn_ds_bpermute(lb4, (int)tw[1][0]);
        unsigned B3 = __builtin_amdgcn_ds_bpermute(lb4, (int)tw[1][1]);
        u32x4 paw;
        paw[0] = use_hi ? B0 : A0;
        paw[1] = use_hi ? B1 : A1;
        paw[2] = use_hi ? B2 : A2;
        paw[3] = use_hi ? B3 : A3;
        frag_ab pa = __builtin_bit_cast(frag_ab, paw);
#pragma unroll
        for (int t2 = 0; t2 < 4; ++t2) {
            const ushort_t* vrow = fTb + (size_t)(t2 * 16 + c) * NP + ps + g * 8;
            pacc[t2] = __builtin_amdgcn_mfma_f32_16x16x32_bf16(pa, *(const frag_ab*)vrow, pacc[t2], 0, 0, 0);
        }
    }

    // in-wave row-sum over g (lane bits 4,5); all lanes end with total for x=c
    rsum += __shfl_xor(rsum, 16);
    rsum += __shfl_xor(rsum, 32);
    if (lane < 16) lds_sum[wv][c] = rsum;
    // PV partials: pacc[t2][r] = PV[x-row g*4+r][e = t2*16+c]
#pragma unroll
    for (int t2 = 0; t2 < 4; ++t2)
#pragma unroll
        for (int r = 0; r < 4; ++r)
            lds_pv[wv][g * 4 + r][t2 * 16 + c] = pacc[t2][r];
    __syncthreads();

    // cross-wave combine: 1024 values over 512 threads (2 each)
#pragma unroll
    for (int k = 0; k < 2; ++k) {
        int v = tid + k * 512;
        int row = v >> 6, e = v & 63;
        float stot = 0.f, val = 0.f;
#pragma unroll
        for (int w = 0; w < 8; ++w) {
            stot += lds_sum[w][row];
            val  += lds_pv[w][row][e];
        }
        facat_b[((size_t)h * NX + xt * 16 + row) * 128 + e] = f2bf(val / stot);
    }
    if (tid < 16) {
        float stot = 0.f;
#pragma unroll
        for (int w = 0; w < 8; ++w) stot += lds_sum[w][tid];
        lds_inv[tid] = 1.f / stot;
    }
    __syncthreads();

    // ---- pass 2: recompute QK for my slice, write normalized w ----
    float inv_c = lds_inv[c];                     // for x = c
    float* wrow = w_out + ((size_t)(xt * 16 + c) * NH + h) * NP;
    for (int ps = p0; ps < p0 + 512; ps += 16) {
        const ushort_t* arow = fpb + (size_t)(ps + c) * FATT + g * 8;
        f32x4 s = {};
        s = __builtin_amdgcn_mfma_f32_16x16x32_bf16(*(const frag_ab*)arow, bx0, s, 0, 0, 0);
        s = __builtin_amdgcn_mfma_f32_16x16x32_bf16(*(const frag_ab*)(arow + 32), bx1, s, 0, 0, 0);
        f32x4 o;
        o[0] = __expf(s[0] * 0.125f) * inv_c;
        o[1] = __expf(s[1] * 0.125f) * inv_c;
        o[2] = __expf(s[2] * 0.125f) * inv_c;
        o[3] = __expf(s[3] * 0.125f) * inv_c;
        __builtin_nontemporal_store(o, (f32x4*)(wrow + ps + g * 4));
    }
}

// ---------------------------------------------------------------------------
// K3: fc — per-head MFMA GEMM (2048 x 64out x 128k), relu, bf16 out
// ---------------------------------------------------------------------------
__global__ __launch_bounds__(256) void k_fc(const ushort_t* __restrict__ facat_b,
                                            const ushort_t* __restrict__ Wfc_b,
                                            const float* __restrict__ bfc,
                                            ushort_t* __restrict__ fcout_b) {
    int tid = threadIdx.x;
    int wv = tid >> 6, lane = tid & 63;
    int g = lane >> 4, c = lane & 15;
    int x0 = blockIdx.x * 64 + wv * 16;
    int h = blockIdx.y;

    const ushort_t* A = facat_b + ((size_t)h * NX + x0 + c) * 128 + g * 8;
    const ushort_t* B = Wfc_b + (size_t)h * FATT * 128;

    f32x4 acc[4] = {};
#pragma unroll
    for (int ks = 0; ks < 128; ks += 32) {
        frag_ab a = *(const frag_ab*)(A + ks);
#pragma unroll
        for (int t = 0; t < 4; ++t) {
            frag_ab b = *(const frag_ab*)(B + (size_t)(t * 16 + c) * 128 + ks + g * 8);
            acc[t] = __builtin_amdgcn_mfma_f32_16x16x32_bf16(a, b, acc[t], 0, 0, 0);
        }
    }
#pragma unroll
    for (int t = 0; t < 4; ++t) {
        int e = t * 16 + c;
        float bia = bfc[h * FATT + e];
#pragma unroll
        for (int r = 0; r < 4; ++r) {
            int x = x0 + g * 4 + r;
            fcout_b[(size_t)x * FDIM + h * FATT + e] = f2bf(fmaxf(acc[t][r] + bia, 0.f));
        }
    }
}

// ---------------------------------------------------------------------------
// K4: out GEMM (2048 x 512 x 512) MFMA + residual + bias + relu (fp32 out)
// ---------------------------------------------------------------------------
__global__ __launch_bounds__(256) void k_out(const float* __restrict__ fx_in,
                                             const ushort_t* __restrict__ fcout_b,
                                             const ushort_t* __restrict__ Wout_b,
                                             const float* __restrict__ bout,
                                             float* __restrict__ out) {
    int tid = threadIdx.x;
    int wv = tid >> 6, lane = tid & 63;
    int g = lane >> 4, c = lane & 15;
    int x0 = blockIdx.x * 64 + wv * 16;
    int o0 = blockIdx.y * 64;

    f32x4 acc[4] = {};
    const ushort_t* A = fcout_b + (size_t)(x0 + c) * FDIM + g * 8;
#pragma unroll 4
    for (int ks = 0; ks < FDIM; ks += 32) {
        frag_ab a = *(const frag_ab*)(A + ks);
#pragma unroll
        for (int t = 0; t < 4; ++t) {
            frag_ab b = *(const frag_ab*)(Wout_b + (size_t)(o0 + t * 16 + c) * FDIM + ks + g * 8);
            acc[t] = __builtin_amdgcn_mfma_f32_16x16x32_bf16(a, b, acc[t], 0, 0, 0);
        }
    }
#pragma unroll
    for (int t = 0; t < 4; ++t) {
        int f = o0 + t * 16 + c;
        float bia = bout[f];
#pragma unroll
        for (int r = 0; r < 4; ++r) {
            int x = x0 + g * 4 + r;
            float v = acc[t][r] + bia + fx_in[(size_t)x * FDIM + f];
            out[(size_t)x * FDIM + f] = fmaxf(v, 0.f);
        }
    }
}

extern "C" void kernel_launch(void* const* d_in, const int* in_sizes, int n_in,
                              void* d_out, int out_size, void* d_ws, size_t ws_size,
                              hipStream_t stream) {
    const float* fx_in = (const float*)d_in[0];
    const float* fp_in = (const float*)d_in[1];
    const float* Wembd = (const float*)d_in[2];
    const float* bembd = (const float*)d_in[3];
    const float* Wfc   = (const float*)d_in[4];
    const float* bfc   = (const float*)d_in[5];
    const float* Wout  = (const float*)d_in[6];
    const float* bout  = (const float*)d_in[7];

    float* out   = (float*)d_out;
    float* w_out = out + (size_t)NX * FDIM;

    ushort_t* f_b     = (ushort_t*)d_ws;                     // 6144*512
    ushort_t* We_b    = f_b + (size_t)NTOT * FDIM;           // 512*512
    ushort_t* femb_b  = We_b + (size_t)FDIM * FDIM;          // 8*6144*64
    ushort_t* fpT_b   = femb_b + (size_t)NH * NTOT * FATT;   // 8*64*4096
    ushort_t* facat_b = fpT_b + (size_t)NH * FATT * NP;      // 8*2048*128
    ushort_t* fcout_b = facat_b + (size_t)NH * NX * 128;     // 2048*512
    ushort_t* Wfc_b   = fcout_b + (size_t)NX * FDIM;         // 8*64*128
    ushort_t* Wout_b  = Wfc_b + (size_t)NH * FATT * 2 * FATT;// 512*512

    k_prep  <<<1024, 256, 0, stream>>>(fx_in, fp_in, Wembd, Wfc, Wout,
                                       f_b, We_b, Wfc_b, Wout_b);
    k_embed <<<dim3(96, 8), 256, 0, stream>>>(f_b, We_b, bembd, femb_b, fpT_b, facat_b);
    k_attn_f<<<1024, 512, 0, stream>>>(femb_b, fpT_b, w_out, facat_b);
    k_fc    <<<dim3(32, 8), 256, 0, stream>>>(facat_b, Wfc_b, bfc, fcout_b);
    k_out   <<<dim3(32, 8), 256, 0, stream>>>(fx_in, fcout_b, Wout_b, bout, out);
}